// Round 12
// baseline (595.804 us; speedup 1.0000x reference)
//
#include <hip/hip_runtime.h>

// Problem constants
#define NB 128
#define NL 1024
#define NE 512
#define NA 512
#define ND 512

typedef __attribute__((ext_vector_type(8))) short short8;
typedef __attribute__((ext_vector_type(4))) float f32x4;

static __device__ __forceinline__ unsigned short f2bf(float f) {
  unsigned int u = __float_as_uint(f);
  u += 0x7FFF + ((u >> 16) & 1);   // round-to-nearest-even
  return (unsigned short)(u >> 16);
}

// ---------------------------------------------------------------------------
// Kernel 1: blocks 0..63 pack W_enc -> bf16 MFMA B-fragment order;
// blocks 64..191: att2[b][a] = dec[b]@W_dec[:,a] + b_dec[a] + b_enc[a].
// Bpack: [ki=0..15][nf=0..31][lane=0..63][j=0..7]
__global__ void k_prep(const float* __restrict__ W_enc,
                       unsigned short* __restrict__ Bpack,
                       const float* __restrict__ dec,
                       const float* __restrict__ Wdec,
                       const float* __restrict__ b_enc,
                       const float* __restrict__ b_dec,
                       float* __restrict__ att2) {
  int blk = blockIdx.x;
  int tid = threadIdx.x;  // 512
  if (blk < 64) {
    int t = blk * 512 + tid;
    int lane = t & 63;
    int rest = t >> 6;
    int nf = rest & 31;
    int ki = rest >> 5;
    int col = nf * 16 + (lane & 15);
    int kbase = ki * 32 + (lane >> 4) * 8;
    short8 v;
#pragma unroll
    for (int j = 0; j < 8; ++j)
      v[j] = (short)f2bf(W_enc[(kbase + j) * NA + col]);
    *reinterpret_cast<short8*>(Bpack + (long)t * 8) = v;
  } else {
    int b = blk - 64;
    int a = tid;
    float acc = b_enc[a] + b_dec[a];
    const float* drow = dec + b * ND;
#pragma unroll 8
    for (int d = 0; d < ND; ++d)
      acc += drow[d] * Wdec[d * NA + a];
    att2[b * NA + a] = acc;
  }
}

// ---------------------------------------------------------------------------
// Kernel 2: persistent fused scores+softmax-partial+PV, BM=128.
// 256 blocks (1/CU) x 1024 thr (16 waves: rg = wave>>3 row-half, cg = wave&7
// col-group; wave = 64 rows x 64 cols, acc[4][4]). 4 rounds of 128 rows.
// B-traffic HALVED vs BM=64 (512 KB per 128 rows). A[128][512] bf16 in LDS
// (XOR swizzle); next round's A loaded+converted into 8 short8 regs (32
// VGPRs) on even K-steps, written to LDS after PV -> no serial staging.
// No barriers in the K-loop. B consumed in reg-pairs to stay <=128 VGPRs.
__global__ __attribute__((amdgpu_waves_per_eu(4))) __launch_bounds__(1024)
void k_main(const float* __restrict__ enc,
            const unsigned short* __restrict__ Bpack,
            const float* __restrict__ att2g, const float* __restrict__ wfull,
            float* __restrict__ attg, float* __restrict__ ogp,
            float* __restrict__ mzg) {
  extern __shared__ char smem[];
  // 0..131072: A [128][512] bf16 swizzled | 131072: red/xch (8KB)
  // 139264: pl (512B) | 139776: mw (8B) | 139784: zw (8B)
  float* red = (float*)(smem + 131072);
  float* pl = (float*)(smem + 139264);
  float* mw = (float*)(smem + 139776);
  float* zw = (float*)(smem + 139784);

  const int t = threadIdx.x;
  const int lane = t & 63;
  const int wave = t >> 6;   // 0..15
  const int l15 = lane & 15;
  const int lq = lane >> 4;
  const int cg = wave & 7;
  const int rg = wave >> 3;
  const int blk = blockIdx.x;          // 0..255
  const int batch = blk >> 1;
  const long rowbase = (long)blk * 512;
  const int srow = t >> 4;             // 0..63
  const int scol8 = t & 15;

  const short8* bp = reinterpret_cast<const short8*>(Bpack);

  // chunk c in [0,8): row = (c&1)*64 + srow, k0 = (c>>1)*128 + scol8*8
#define A_CVT(GA, GB, DST)                                                    \
  {                                                                           \
    short8 o_;                                                                \
    o_[0] = (short)f2bf(GA.x); o_[1] = (short)f2bf(GA.y);                     \
    o_[2] = (short)f2bf(GA.z); o_[3] = (short)f2bf(GA.w);                     \
    o_[4] = (short)f2bf(GB.x); o_[5] = (short)f2bf(GB.y);                     \
    o_[6] = (short)f2bf(GB.z); o_[7] = (short)f2bf(GB.w);                     \
    DST = o_;                                                                 \
  }
#define A_STORE(C, V)                                                         \
  {                                                                           \
    int row_ = ((C)&1) * 64 + srow;                                           \
    int k0_ = ((C) >> 1) * 128 + scol8 * 8;                                   \
    int byt_ = (row_ * 1024 + k0_ * 2) ^ ((row_ & 7) << 4);                   \
    *reinterpret_cast<short8*>(smem + byt_) = V;                              \
  }
#define A_GLOAD(C, TROW0, GA, GB)                                             \
  {                                                                           \
    int row_ = ((C)&1) * 64 + srow;                                           \
    int k0_ = ((C) >> 1) * 128 + scol8 * 8;                                   \
    const float* src_ = enc + (TROW0 + row_) * NE + k0_;                      \
    GA = *reinterpret_cast<const float4*>(src_);                              \
    GB = *reinterpret_cast<const float4*>(src_ + 4);                          \
  }

  // ---- prologue: stage tile 0 directly ----
  {
#pragma unroll
    for (int c = 0; c < 8; ++c) {
      float4 ga, gb;
      A_GLOAD(c, rowbase, ga, gb)
      short8 v;
      A_CVT(ga, gb, v)
      A_STORE(c, v)
    }
  }
  __syncthreads();

  f32x4 acc[4][4];
  short8 hA[8];

#define K_STEP(KI)                                                            \
  {                                                                           \
    const int bb_ = (KI)*32 + cg * 4;                                         \
    short8 bv0 = bp[(bb_ + 0) * 64 + lane];                                   \
    short8 bv1 = bp[(bb_ + 1) * 64 + lane];                                   \
    _Pragma("unroll") for (int rt = 0; rt < 4; ++rt) {                        \
      int row_ = rg * 64 + rt * 16 + l15;                                     \
      int byt_ = (row_ * 1024 + (KI)*64 + lq * 16) ^ ((row_ & 7) << 4);       \
      short8 av = *reinterpret_cast<const short8*>(smem + byt_);              \
      acc[rt][0] = __builtin_amdgcn_mfma_f32_16x16x32_bf16(av, bv0, acc[rt][0], 0, 0, 0); \
      acc[rt][1] = __builtin_amdgcn_mfma_f32_16x16x32_bf16(av, bv1, acc[rt][1], 0, 0, 0); \
    }                                                                         \
    short8 bv2 = bp[(bb_ + 2) * 64 + lane];                                   \
    short8 bv3 = bp[(bb_ + 3) * 64 + lane];                                   \
    _Pragma("unroll") for (int rt = 0; rt < 4; ++rt) {                        \
      int row_ = rg * 64 + rt * 16 + l15;                                     \
      int byt_ = (row_ * 1024 + (KI)*64 + lq * 16) ^ ((row_ & 7) << 4);       \
      short8 av = *reinterpret_cast<const short8*>(smem + byt_);              \
      acc[rt][2] = __builtin_amdgcn_mfma_f32_16x16x32_bf16(av, bv2, acc[rt][2], 0, 0, 0); \
      acc[rt][3] = __builtin_amdgcn_mfma_f32_16x16x32_bf16(av, bv3, acc[rt][3], 0, 0, 0); \
    }                                                                         \
  }

#pragma unroll 1
  for (int T = 0; T < 4; ++T) {
    const long tg = (long)blk * 4 + T;
    const long nextrow0 = rowbase + (T + 1) * 128;

#pragma unroll
    for (int rt = 0; rt < 4; ++rt)
#pragma unroll
      for (int cf = 0; cf < 4; ++cf) acc[rt][cf] = (f32x4){0.f, 0.f, 0.f, 0.f};

    // ---- K-loop (no barriers); stage next tile's A on even steps ----
#pragma unroll
    for (int S = 0; S < 16; ++S) {
      if ((S & 1) == 0 && T < 3) {
        float4 ga, gb;
        A_GLOAD(S >> 1, nextrow0, ga, gb)
        A_CVT(ga, gb, hA[S >> 1])
      }
      K_STEP(S)
    }

    // ---- epilogue ----
    float px[4][4];
    {
      float a2r[4], wfr[4];
#pragma unroll
      for (int cf = 0; cf < 4; ++cf) {
        int col = cg * 64 + cf * 16 + l15;
        a2r[cf] = att2g[batch * NA + col];
        wfr[cf] = wfull[col];
      }
#pragma unroll
      for (int rt = 0; rt < 4; ++rt)
#pragma unroll
        for (int r = 0; r < 4; ++r) px[rt][r] = 0.f;
#pragma unroll
      for (int cf = 0; cf < 4; ++cf) {
#pragma unroll
        for (int rt = 0; rt < 4; ++rt)
#pragma unroll
          for (int r = 0; r < 4; ++r) {
            float v = acc[rt][cf][r] + a2r[cf];
            px[rt][r] += fmaxf(v, 0.f) * wfr[cf];
          }
      }
#pragma unroll
      for (int rt = 0; rt < 4; ++rt)
#pragma unroll
        for (int r = 0; r < 4; ++r) {
          float p_ = px[rt][r];
          p_ += __shfl_xor(p_, 1);
          p_ += __shfl_xor(p_, 2);
          p_ += __shfl_xor(p_, 4);
          p_ += __shfl_xor(p_, 8);
          px[rt][r] = p_;
        }
      if (l15 == 0) {
#pragma unroll
        for (int rt = 0; rt < 4; ++rt)
#pragma unroll
          for (int r = 0; r < 4; ++r)
            red[wave * 64 + rt * 16 + lq * 4 + r] = px[rt][r];
      }
    }
    __syncthreads();   // B1: red complete

    // scores, tile max (t<128: waves 0,1)
    float sc = 0.f;
    if (t < 128) {
      int rgi = t >> 6, r6 = t & 63;
#pragma unroll
      for (int c8 = 0; c8 < 8; ++c8) sc += red[(rgi * 8 + c8) * 64 + r6];
      attg[tg * 128 + t] = sc;
      float mloc = sc;
#pragma unroll
      for (int off = 1; off < 64; off <<= 1)
        mloc = fmaxf(mloc, __shfl_xor(mloc, off));
      if (lane == 0) mw[wave] = mloc;
    }
    __syncthreads();   // B2: mw complete
    if (t < 128) {
      float m = fmaxf(mw[0], mw[1]);
      float p = expf(sc - m);
      pl[t] = p;
      float zloc = p;
#pragma unroll
      for (int off = 1; off < 64; off <<= 1) zloc += __shfl_xor(zloc, off);
      if (lane == 0) zw[wave] = zloc;
    }
    __syncthreads();   // B3: pl, zw complete
    if (t == 0) {
      mzg[tg * 2] = fmaxf(mw[0], mw[1]);
      mzg[tg * 2 + 1] = zw[0] + zw[1];
    }

    // PV: 4 row-groups of 32; e = (t&255)*2
    {
      int qg = t >> 8;
      int e = (t & 255) * 2;
      float o0 = 0.f, o1 = 0.f;
#pragma unroll
      for (int i = 0; i < 32; ++i) {
        int row = qg * 32 + i;
        float pw = pl[row];
        int byt = (row * 1024 + e * 2) ^ ((row & 7) << 4);
        unsigned u = *reinterpret_cast<const unsigned*>(smem + byt);
        o0 += pw * __uint_as_float(u << 16);
        o1 += pw * __uint_as_float(u & 0xffff0000u);
      }
      float2* xch = (float2*)red;
      if (qg > 0) xch[(qg - 1) * 256 + (t & 255)] = make_float2(o0, o1);
      __syncthreads();   // B4: xch complete; all PV A-reads done
      if (qg == 0) {
        float2 s1 = xch[t & 255];
        float2 s2 = xch[256 + (t & 255)];
        float2 s3 = xch[512 + (t & 255)];
        *reinterpret_cast<float2*>(ogp + tg * 512 + e) =
            make_float2(o0 + s1.x + s2.x + s3.x, o1 + s1.y + s2.y + s3.y);
      }
    }

    if (T < 3) {
      // stage next tile's A from regs (A-reads all done at B4)
#pragma unroll
      for (int c = 0; c < 8; ++c) A_STORE(c, hA[c])
      __syncthreads();   // B5: A staged for next round
    }
  }
#undef K_STEP
#undef A_GLOAD
#undef A_STORE
#undef A_CVT
}

// ---------------------------------------------------------------------------
// Kernel 3: merge 8 per-tile (m,Z,o) partials per batch; emit weighted+alpha.
__global__ void k_final(const float* __restrict__ attg,
                        const float* __restrict__ ogp,
                        const float* __restrict__ mzg,
                        float* __restrict__ weighted,
                        float* __restrict__ alpha) {
  int b = blockIdx.x;   // 0..127
  int t = threadIdx.x;  // 512
  float mv[8], zv[8];
  float m = -__builtin_huge_valf();
#pragma unroll
  for (int i = 0; i < 8; ++i) {
    mv[i] = mzg[(b * 8 + i) * 2];
    zv[i] = mzg[(b * 8 + i) * 2 + 1];
    m = fmaxf(m, mv[i]);
  }
  float Z = 0.f;
#pragma unroll
  for (int i = 0; i < 8; ++i) {
    float s = expf(mv[i] - m);
    mv[i] = s;
    Z += s * zv[i];
  }
  float inv = 1.f / Z;
  float o = 0.f;
#pragma unroll
  for (int i = 0; i < 8; ++i) o += mv[i] * ogp[((long)b * 8 + i) * 512 + t];
  weighted[b * NE + t] = o * inv;
  int l0 = t, l1 = t + 512;
  alpha[b * NL + l0] =
      expf(attg[((long)b * 8 + (l0 >> 7)) * 128 + (l0 & 127)] - m) * inv;
  alpha[b * NL + l1] =
      expf(attg[((long)b * 8 + (l1 >> 7)) * 128 + (l1 & 127)] - m) * inv;
}

// ---------------------------------------------------------------------------
extern "C" void kernel_launch(void* const* d_in, const int* in_sizes, int n_in,
                              void* d_out, int out_size, void* d_ws, size_t ws_size,
                              hipStream_t stream) {
  const float* enc    = (const float*)d_in[0];  // [B,L,E]
  const float* dec    = (const float*)d_in[1];  // [B,D]
  const float* W_enc  = (const float*)d_in[2];  // [E,A]
  const float* b_enc  = (const float*)d_in[3];  // [A]
  const float* W_dec  = (const float*)d_in[4];  // [D,A]
  const float* b_dec  = (const float*)d_in[5];  // [A]
  const float* W_full = (const float*)d_in[6];  // [A]
  // d_in[7] = b_full: cancels in softmax, unused.

  float* out = (float*)d_out;
  float* weighted = out;                 // [B,E]
  float* alpha = out + NB * NE;          // [B,L]

  char* ws = (char*)d_ws;
  float* att2          = (float*)ws;                           // 256 KB
  unsigned short* Bpk  = (unsigned short*)(ws + (256 << 10));  // 512 KB
  float* attg          = (float*)(ws + (768 << 10));           // 512 KB
  float* ogp           = (float*)(ws + (1280 << 10));          // 2 MB
  float* mzg           = (float*)(ws + (3328 << 10));          // 8 KB

  hipLaunchKernelGGL(k_prep, dim3(192), dim3(512), 0, stream,
                     W_enc, Bpk, dec, W_dec, b_enc, b_dec, att2);
  hipLaunchKernelGGL(k_main, dim3(256), dim3(1024), 139808, stream,
                     enc, Bpk, att2, W_full, attg, ogp, mzg);
  hipLaunchKernelGGL(k_final, dim3(NB), dim3(512), 0, stream,
                     attg, ogp, mzg, weighted, alpha);
}

// Round 13
// 468.608 us; speedup vs baseline: 1.2714x; 1.2714x over previous
//
#include <hip/hip_runtime.h>

// Problem constants
#define NB 128
#define NL 1024
#define NE 512
#define NA 512
#define ND 512

typedef __attribute__((ext_vector_type(8))) short short8;
typedef __attribute__((ext_vector_type(4))) float f32x4;

static __device__ __forceinline__ unsigned short f2bf(float f) {
  unsigned int u = __float_as_uint(f);
  u += 0x7FFF + ((u >> 16) & 1);   // round-to-nearest-even
  return (unsigned short)(u >> 16);
}

// ---------------------------------------------------------------------------
// Kernel 1: blocks 0..63 pack W_enc -> bf16 MFMA B-fragment order;
// blocks 64..191: att2[b][a] = dec[b]@W_dec[:,a] + b_dec[a] + b_enc[a].
// Bpack: [ki=0..15][nf=0..31][lane=0..63][j=0..7]
__global__ void k_prep(const float* __restrict__ W_enc,
                       unsigned short* __restrict__ Bpack,
                       const float* __restrict__ dec,
                       const float* __restrict__ Wdec,
                       const float* __restrict__ b_enc,
                       const float* __restrict__ b_dec,
                       float* __restrict__ att2) {
  int blk = blockIdx.x;
  int tid = threadIdx.x;  // 512
  if (blk < 64) {
    int t = blk * 512 + tid;
    int lane = t & 63;
    int rest = t >> 6;
    int nf = rest & 31;
    int ki = rest >> 5;
    int col = nf * 16 + (lane & 15);
    int kbase = ki * 32 + (lane >> 4) * 8;
    short8 v;
#pragma unroll
    for (int j = 0; j < 8; ++j)
      v[j] = (short)f2bf(W_enc[(kbase + j) * NA + col]);
    *reinterpret_cast<short8*>(Bpack + (long)t * 8) = v;
  } else {
    int b = blk - 64;
    int a = tid;
    float acc = b_enc[a] + b_dec[a];
    const float* drow = dec + b * ND;
#pragma unroll 8
    for (int d = 0; d < ND; ++d)
      acc += drow[d] * Wdec[d * NA + a];
    att2[b * NA + a] = acc;
  }
}

// ---------------------------------------------------------------------------
// Kernel 2: persistent producer/consumer fused scores+softmax-partial+PV.
// 256 blocks (1/CU) x 1024 thr (16 waves). Waves 0-7 = CONSUMERS (R10's
// proven K-loop: wave = 64 rows x 64 cols, acc[4][4]); waves 8-15 =
// PRODUCERS (load+convert NEXT tile's A fp32->bf16 into the other half of a
// 2x64KB double-buffered LDS A). Producers span the whole tile -> HBM issue
// continuous; tile time = HBM fair-share; MFMA/L2-B hide under it.
// Role split by wave -> consumers need no staging regs, producers no acc ->
// no spill at the 128-VGPR cap (pinned via waves_per_eu(4,4)).
// 3 barriers/tile. Epilogue identical math to R10 (passing).
__global__ __attribute__((amdgpu_waves_per_eu(4, 4))) __launch_bounds__(1024)
void k_main(const float* __restrict__ enc,
            const unsigned short* __restrict__ Bpack,
            const float* __restrict__ att2g, const float* __restrict__ wfull,
            float* __restrict__ attg, float* __restrict__ ogp,
            float* __restrict__ mzg) {
  extern __shared__ char smem[];
  // 0..131072: A double buffer (2 x 64KB, row-major bf16 [64][512], XOR swz)
  // 131072: red (2KB) / xch (6KB, later phase) | 137216: pl (256B)
  float* red = (float*)(smem + 131072);
  float* pl = (float*)(smem + 137216);

  const int t = threadIdx.x;
  const int lane = t & 63;
  const int wave = t >> 6;   // 0..15
  const int l15 = lane & 15;
  const int lq = lane >> 4;
  const int blk = blockIdx.x;          // 0..255
  const int batch = blk >> 1;
  const long rowbase = (long)blk * 512;

  const short8* bp = reinterpret_cast<const short8*>(Bpack);

  float a2r[4], wfr[4];
#pragma unroll
  for (int cf = 0; cf < 4; ++cf) {
    int col = (wave & 7) * 64 + cf * 16 + l15;
    a2r[cf] = att2g[batch * NA + col];
    wfr[cf] = wfull[col];
  }

  // ---- prologue: all 1024 threads stage tile 0 into buf0 ----
  {
    int row = t >> 4;          // 0..63
    int oct0 = t & 15;         // 0..15
    float4 ga[4], gb[4];
#pragma unroll
    for (int j = 0; j < 4; ++j) {
      int oct = oct0 + j * 16;
      const float* src = enc + (rowbase + row) * NE + oct * 8;
      ga[j] = *reinterpret_cast<const float4*>(src);
      gb[j] = *reinterpret_cast<const float4*>(src + 4);
    }
#pragma unroll
    for (int j = 0; j < 4; ++j) {
      int oct = oct0 + j * 16;
      short8 o;
      o[0] = (short)f2bf(ga[j].x); o[1] = (short)f2bf(ga[j].y);
      o[2] = (short)f2bf(ga[j].z); o[3] = (short)f2bf(ga[j].w);
      o[4] = (short)f2bf(gb[j].x); o[5] = (short)f2bf(gb[j].y);
      o[6] = (short)f2bf(gb[j].z); o[7] = (short)f2bf(gb[j].w);
      int byt = (row * 1024 + oct * 16) ^ ((row & 7) << 4);
      *reinterpret_cast<short8*>(smem + byt) = o;
    }
  }
  __syncthreads();

  f32x4 acc[4][4];

#pragma unroll 1
  for (int T = 0; T < 8; ++T) {
    const long tg = (long)blk * 8 + T;
    const int abase = (T & 1) * 65536;

    if (wave < 8) {
      // ================= CONSUMER: K-loop + scores =================
#pragma unroll
      for (int rt = 0; rt < 4; ++rt)
#pragma unroll
        for (int cf = 0; cf < 4; ++cf) acc[rt][cf] = (f32x4){0.f, 0.f, 0.f, 0.f};
#pragma unroll
      for (int KI = 0; KI < 16; ++KI) {
        const int bb = KI * 32 + (wave & 7) * 4;
        short8 bv0 = bp[(bb + 0) * 64 + lane];
        short8 bv1 = bp[(bb + 1) * 64 + lane];
        short8 bv2 = bp[(bb + 2) * 64 + lane];
        short8 bv3 = bp[(bb + 3) * 64 + lane];
#pragma unroll
        for (int rt = 0; rt < 4; ++rt) {
          int row = rt * 16 + l15;
          int byt = abase + ((row * 1024 + KI * 64 + lq * 16) ^ ((row & 7) << 4));
          short8 av = *reinterpret_cast<const short8*>(smem + byt);
          acc[rt][0] = __builtin_amdgcn_mfma_f32_16x16x32_bf16(av, bv0, acc[rt][0], 0, 0, 0);
          acc[rt][1] = __builtin_amdgcn_mfma_f32_16x16x32_bf16(av, bv1, acc[rt][1], 0, 0, 0);
          acc[rt][2] = __builtin_amdgcn_mfma_f32_16x16x32_bf16(av, bv2, acc[rt][2], 0, 0, 0);
          acc[rt][3] = __builtin_amdgcn_mfma_f32_16x16x32_bf16(av, bv3, acc[rt][3], 0, 0, 0);
        }
      }
      // scores: relu(acc+att2)*wfull, reduce over this wave's 64 cols
      float px[4][4];
#pragma unroll
      for (int rt = 0; rt < 4; ++rt)
#pragma unroll
        for (int r = 0; r < 4; ++r) px[rt][r] = 0.f;
#pragma unroll
      for (int cf = 0; cf < 4; ++cf) {
#pragma unroll
        for (int rt = 0; rt < 4; ++rt)
#pragma unroll
          for (int r = 0; r < 4; ++r) {
            float v = acc[rt][cf][r] + a2r[cf];
            px[rt][r] += fmaxf(v, 0.f) * wfr[cf];
          }
      }
#pragma unroll
      for (int rt = 0; rt < 4; ++rt)
#pragma unroll
        for (int r = 0; r < 4; ++r) {
          float p_ = px[rt][r];
          p_ += __shfl_xor(p_, 1);
          p_ += __shfl_xor(p_, 2);
          p_ += __shfl_xor(p_, 4);
          p_ += __shfl_xor(p_, 8);
          px[rt][r] = p_;
        }
      if (l15 == 0) {
#pragma unroll
        for (int rt = 0; rt < 4; ++rt)
#pragma unroll
          for (int r = 0; r < 4; ++r)
            red[wave * 64 + rt * 16 + lq * 4 + r] = px[rt][r];
      }
    } else if (T < 7) {
      // ================= PRODUCER: stage tile T+1 =================
      int ps = t - 512;          // 0..511
      int row = ps >> 3;         // 0..63
      int oct0 = ps & 7;         // 0..7
      const long srow0 = rowbase + (T + 1) * 64;
      const int nbase = ((T + 1) & 1) * 65536;
      float4 ga[8], gb[8];
#pragma unroll
      for (int j = 0; j < 8; ++j) {
        int oct = oct0 + j * 8;
        const float* src = enc + (srow0 + row) * NE + oct * 8;
        ga[j] = *reinterpret_cast<const float4*>(src);
        gb[j] = *reinterpret_cast<const float4*>(src + 4);
      }
#pragma unroll
      for (int j = 0; j < 8; ++j) {
        int oct = oct0 + j * 8;
        short8 o;
        o[0] = (short)f2bf(ga[j].x); o[1] = (short)f2bf(ga[j].y);
        o[2] = (short)f2bf(ga[j].z); o[3] = (short)f2bf(ga[j].w);
        o[4] = (short)f2bf(gb[j].x); o[5] = (short)f2bf(gb[j].y);
        o[6] = (short)f2bf(gb[j].z); o[7] = (short)f2bf(gb[j].w);
        int byt = nbase + ((row * 1024 + oct * 16) ^ ((row & 7) << 4));
        *reinterpret_cast<short8*>(smem + byt) = o;
      }
    }
    __syncthreads();   // B1: red ready; next-tile A staged

    // ---- shared epilogue (all 16 waves; math identical to R10) ----
    float sc = 0.f;
#pragma unroll
    for (int w8 = 0; w8 < 8; ++w8) sc += red[w8 * 64 + lane];
    if (t < 64) attg[tg * 64 + t] = sc;
    float m = sc;
#pragma unroll
    for (int off = 1; off < 64; off <<= 1) m = fmaxf(m, __shfl_xor(m, off));
    float p = expf(sc - m);
    float Z = p;
#pragma unroll
    for (int off = 1; off < 64; off <<= 1) Z += __shfl_xor(Z, off);
    if (t < 64) pl[t] = p;
    __syncthreads();   // B2: pl ready; red free for xch reuse

    // PV across 1024 threads: qg = t>>8 owns 16 rows; e pair = (t&255)*2
    {
      int qg = t >> 8;
      int e = (t & 255) * 2;
      float o0 = 0.f, o1 = 0.f;
#pragma unroll
      for (int i = 0; i < 16; ++i) {
        int row = qg * 16 + i;
        float pw = pl[row];
        int byt = abase + ((row * 1024 + e * 2) ^ ((row & 7) << 4));
        unsigned u = *reinterpret_cast<const unsigned*>(smem + byt);
        o0 += pw * __uint_as_float(u << 16);
        o1 += pw * __uint_as_float(u & 0xffff0000u);
      }
      float2* xch = (float2*)red;
      if (qg > 0) xch[(qg - 1) * 256 + (t & 255)] = make_float2(o0, o1);
      __syncthreads();   // B3: xch ready; all A-reads of buf[T&1] done
      if (qg == 0) {
        float2 s1 = xch[t & 255];
        float2 s2 = xch[256 + (t & 255)];
        float2 s3 = xch[512 + (t & 255)];
        *reinterpret_cast<float2*>(ogp + tg * 512 + e) =
            make_float2(o0 + s1.x + s2.x + s3.x, o1 + s1.y + s2.y + s3.y);
      }
      if (t == 0) {
        mzg[tg * 2] = m;
        mzg[tg * 2 + 1] = Z;
      }
    }
  }
}

// ---------------------------------------------------------------------------
// Kernel 3: merge 16 per-tile (m,Z,o) partials per batch; emit weighted+alpha.
__global__ void k_final(const float* __restrict__ attg,
                        const float* __restrict__ ogp,
                        const float* __restrict__ mzg,
                        float* __restrict__ weighted,
                        float* __restrict__ alpha) {
  int b = blockIdx.x;   // 0..127
  int t = threadIdx.x;  // 512
  float mv[16], zv[16];
  float m = -__builtin_huge_valf();
#pragma unroll
  for (int i = 0; i < 16; ++i) {
    mv[i] = mzg[(b * 16 + i) * 2];
    zv[i] = mzg[(b * 16 + i) * 2 + 1];
    m = fmaxf(m, mv[i]);
  }
  float Z = 0.f;
#pragma unroll
  for (int i = 0; i < 16; ++i) {
    float s = expf(mv[i] - m);
    mv[i] = s;
    Z += s * zv[i];
  }
  float inv = 1.f / Z;
  float o = 0.f;
#pragma unroll
  for (int i = 0; i < 16; ++i) o += mv[i] * ogp[((long)b * 16 + i) * 512 + t];
  weighted[b * NE + t] = o * inv;
  alpha[b * NL + t] = expf(attg[b * NL + t] - m) * inv;
  alpha[b * NL + 512 + t] = expf(attg[b * NL + 512 + t] - m) * inv;
}

// ---------------------------------------------------------------------------
extern "C" void kernel_launch(void* const* d_in, const int* in_sizes, int n_in,
                              void* d_out, int out_size, void* d_ws, size_t ws_size,
                              hipStream_t stream) {
  const float* enc    = (const float*)d_in[0];  // [B,L,E]
  const float* dec    = (const float*)d_in[1];  // [B,D]
  const float* W_enc  = (const float*)d_in[2];  // [E,A]
  const float* b_enc  = (const float*)d_in[3];  // [A]
  const float* W_dec  = (const float*)d_in[4];  // [D,A]
  const float* b_dec  = (const float*)d_in[5];  // [A]
  const float* W_full = (const float*)d_in[6];  // [A]
  // d_in[7] = b_full: cancels in softmax, unused.

  float* out = (float*)d_out;
  float* weighted = out;                 // [B,E]
  float* alpha = out + NB * NE;          // [B,L]

  char* ws = (char*)d_ws;
  float* att2          = (float*)ws;                           // 256 KB
  unsigned short* Bpk  = (unsigned short*)(ws + (256 << 10));  // 512 KB
  float* attg          = (float*)(ws + (768 << 10));           // 512 KB
  float* ogp           = (float*)(ws + (1280 << 10));          // 4 MB
  float* mzg           = (float*)(ws + (5376 << 10));          // 16 KB

  hipLaunchKernelGGL(k_prep, dim3(192), dim3(512), 0, stream,
                     W_enc, Bpk, dec, W_dec, b_enc, b_dec, att2);
  hipLaunchKernelGGL(k_main, dim3(256), dim3(1024), 137472, stream,
                     enc, Bpk, att2, W_full, attg, ogp, mzg);
  hipLaunchKernelGGL(k_final, dim3(NB), dim3(512), 0, stream,
                     attg, ogp, mzg, weighted, alpha);
}

// Round 14
// 129.690 us; speedup vs baseline: 4.5941x; 3.6133x over previous
//
#include <hip/hip_runtime.h>

// Problem constants
#define NB 128
#define NL 1024
#define NE 512
#define NA 512
#define ND 512

typedef __attribute__((ext_vector_type(8))) short short8;
typedef __attribute__((ext_vector_type(4))) float f32x4;

static __device__ __forceinline__ unsigned short f2bf(float f) {
  unsigned int u = __float_as_uint(f);
  u += 0x7FFF + ((u >> 16) & 1);   // round-to-nearest-even
  return (unsigned short)(u >> 16);
}

// ---------------------------------------------------------------------------
// Kernel 1: blocks 0..63 pack W_enc -> bf16 MFMA B-fragment order;
// blocks 64..191: att2[b][a] = dec[b]@W_dec[:,a] + b_dec[a] + b_enc[a].
// Bpack: [ki=0..15][nf=0..31][lane=0..63][j=0..7]
__global__ void k_prep(const float* __restrict__ W_enc,
                       unsigned short* __restrict__ Bpack,
                       const float* __restrict__ dec,
                       const float* __restrict__ Wdec,
                       const float* __restrict__ b_enc,
                       const float* __restrict__ b_dec,
                       float* __restrict__ att2) {
  int blk = blockIdx.x;
  int tid = threadIdx.x;  // 512
  if (blk < 64) {
    int t = blk * 512 + tid;
    int lane = t & 63;
    int rest = t >> 6;
    int nf = rest & 31;
    int ki = rest >> 5;
    int col = nf * 16 + (lane & 15);
    int kbase = ki * 32 + (lane >> 4) * 8;
    short8 v;
#pragma unroll
    for (int j = 0; j < 8; ++j)
      v[j] = (short)f2bf(W_enc[(kbase + j) * NA + col]);
    *reinterpret_cast<short8*>(Bpack + (long)t * 8) = v;
  } else {
    int b = blk - 64;
    int a = tid;
    float acc = b_enc[a] + b_dec[a];
    const float* drow = dec + b * ND;
#pragma unroll 8
    for (int d = 0; d < ND; ++d)
      acc += drow[d] * Wdec[d * NA + a];
    att2[b * NA + a] = acc;
  }
}

// ---------------------------------------------------------------------------
// Kernel 2: fused scores + per-block softmax-partial + PV (R10 structure).
// 2048 blocks x 64 rows, 512 thr (8 waves), 2 blocks/CU. K-interleaved A
// staging (prologue q0,q1; q2,q3 during ki0-7; barrier at ki8). NEW vs R10:
// named depth-1 B double-buffer (bA*/bB*) -> ki+1's 4 B-fragments load from
// L2 while ki's 16 MFMAs run. Peak live regs ~124 <= 128 cap, pinned via
// waves_per_eu(4,4) (R12/R13 lesson: pin BOTH bounds).
__global__ __attribute__((amdgpu_waves_per_eu(4, 4))) __launch_bounds__(512)
void k_main(const float* __restrict__ enc,
            const unsigned short* __restrict__ Bpack,
            const float* __restrict__ att2g, const float* __restrict__ wfull,
            float* __restrict__ attg, float* __restrict__ ogp,
            float* __restrict__ mzg) {
  extern __shared__ char smem[];       // 64KB A | 2KB red | 256B p
  const int t = threadIdx.x;
  const int lane = t & 63;
  const int wave = t >> 6;
  const int l15 = lane & 15;
  const int lq = lane >> 4;
  const int blk = blockIdx.x;          // 0..2047
  const int batch = blk >> 4;          // 16 blocks per batch
  const long row0 = (long)blk * 64;
  const int srow16 = t >> 4;           // 0..31 (staging row within half)
  const int scol8 = t & 15;            // staging col8

  // Staging chunk (Q, FI): row = FI*32 + srow16, k0 = Q*128 + scol8*8.
#define G_LOAD(Q, FI, GA, GB)                                                 \
  {                                                                           \
    int row = (FI)*32 + srow16;                                               \
    const float* src = enc + (row0 + row) * NE + (Q)*128 + scol8 * 8;         \
    GA = *reinterpret_cast<const float4*>(src);                               \
    GB = *reinterpret_cast<const float4*>(src + 4);                           \
  }
#define G_WRITE(Q, FI, GA, GB)                                                \
  {                                                                           \
    int row = (FI)*32 + srow16;                                               \
    short8 o;                                                                 \
    o[0] = (short)f2bf(GA.x); o[1] = (short)f2bf(GA.y);                       \
    o[2] = (short)f2bf(GA.z); o[3] = (short)f2bf(GA.w);                       \
    o[4] = (short)f2bf(GB.x); o[5] = (short)f2bf(GB.y);                       \
    o[6] = (short)f2bf(GB.z); o[7] = (short)f2bf(GB.w);                       \
    int byt = (row * 1024 + (Q)*256 + scol8 * 16) ^ ((row & 7) << 4);         \
    *reinterpret_cast<short8*>(smem + byt) = o;                               \
  }

  // ---- prologue: stage quarters 0,1 (k 0..255) ----
  {
    float4 h[8];
#pragma unroll
    for (int c = 0; c < 4; ++c) {
      int q = c >> 1;
      int row = (c & 1) * 32 + srow16;
      const float* src = enc + (row0 + row) * NE + q * 128 + scol8 * 8;
      h[c * 2] = *reinterpret_cast<const float4*>(src);
      h[c * 2 + 1] = *reinterpret_cast<const float4*>(src + 4);
    }
#pragma unroll
    for (int c = 0; c < 4; ++c) {
      int q = c >> 1;
      int row = (c & 1) * 32 + srow16;
      float4 xa = h[c * 2], xb = h[c * 2 + 1];
      short8 o;
      o[0] = (short)f2bf(xa.x); o[1] = (short)f2bf(xa.y);
      o[2] = (short)f2bf(xa.z); o[3] = (short)f2bf(xa.w);
      o[4] = (short)f2bf(xb.x); o[5] = (short)f2bf(xb.y);
      o[6] = (short)f2bf(xb.z); o[7] = (short)f2bf(xb.w);
      int byt = (row * 1024 + q * 256 + scol8 * 16) ^ ((row & 7) << 4);
      *reinterpret_cast<short8*>(smem + byt) = o;
    }
  }
  __syncthreads();

  f32x4 acc[4][4];
#pragma unroll
  for (int rt = 0; rt < 4; ++rt)
#pragma unroll
    for (int cf = 0; cf < 4; ++cf) acc[rt][cf] = (f32x4){0.f, 0.f, 0.f, 0.f};

  const short8* bp = reinterpret_cast<const short8*>(Bpack);
#define B_LOAD(KI, B0, B1, B2, B3)                                            \
  B0 = bp[((KI)*32 + wave * 4 + 0) * 64 + lane];                              \
  B1 = bp[((KI)*32 + wave * 4 + 1) * 64 + lane];                              \
  B2 = bp[((KI)*32 + wave * 4 + 2) * 64 + lane];                              \
  B3 = bp[((KI)*32 + wave * 4 + 3) * 64 + lane];

#define K_MFMA(KI, B0, B1, B2, B3)                                            \
  {                                                                           \
    _Pragma("unroll") for (int rt = 0; rt < 4; ++rt) {                        \
      int row = rt * 16 + l15;                                                \
      int byt = (row * 1024 + (KI)*64 + lq * 16) ^ ((row & 7) << 4);          \
      short8 av = *reinterpret_cast<const short8*>(smem + byt);               \
      acc[rt][0] = __builtin_amdgcn_mfma_f32_16x16x32_bf16(av, B0, acc[rt][0], 0, 0, 0); \
      acc[rt][1] = __builtin_amdgcn_mfma_f32_16x16x32_bf16(av, B1, acc[rt][1], 0, 0, 0); \
      acc[rt][2] = __builtin_amdgcn_mfma_f32_16x16x32_bf16(av, B2, acc[rt][2], 0, 0, 0); \
      acc[rt][3] = __builtin_amdgcn_mfma_f32_16x16x32_bf16(av, B3, acc[rt][3], 0, 0, 0); \
    }                                                                         \
  }

  {
    short8 bA0, bA1, bA2, bA3, bB0, bB1, bB2, bB3;
    B_LOAD(0, bA0, bA1, bA2, bA3)
    {
      float4 g0, g1, g2, g3;
      B_LOAD(1, bB0, bB1, bB2, bB3) G_LOAD(2, 0, g0, g1) K_MFMA(0, bA0, bA1, bA2, bA3)
      B_LOAD(2, bA0, bA1, bA2, bA3) G_LOAD(2, 1, g2, g3) K_MFMA(1, bB0, bB1, bB2, bB3)
      B_LOAD(3, bB0, bB1, bB2, bB3) G_WRITE(2, 0, g0, g1) K_MFMA(2, bA0, bA1, bA2, bA3)
      B_LOAD(4, bA0, bA1, bA2, bA3) G_WRITE(2, 1, g2, g3) K_MFMA(3, bB0, bB1, bB2, bB3)
      B_LOAD(5, bB0, bB1, bB2, bB3) G_LOAD(3, 0, g0, g1) K_MFMA(4, bA0, bA1, bA2, bA3)
      B_LOAD(6, bA0, bA1, bA2, bA3) G_LOAD(3, 1, g2, g3) K_MFMA(5, bB0, bB1, bB2, bB3)
      B_LOAD(7, bB0, bB1, bB2, bB3) G_WRITE(3, 0, g0, g1) K_MFMA(6, bA0, bA1, bA2, bA3)
      B_LOAD(8, bA0, bA1, bA2, bA3) G_WRITE(3, 1, g2, g3) K_MFMA(7, bB0, bB1, bB2, bB3)
    }
    __syncthreads();   // quarters 2,3 staged by all waves before ki8 reads
    B_LOAD(9, bB0, bB1, bB2, bB3)   K_MFMA(8, bA0, bA1, bA2, bA3)
    B_LOAD(10, bA0, bA1, bA2, bA3)  K_MFMA(9, bB0, bB1, bB2, bB3)
    B_LOAD(11, bB0, bB1, bB2, bB3)  K_MFMA(10, bA0, bA1, bA2, bA3)
    B_LOAD(12, bA0, bA1, bA2, bA3)  K_MFMA(11, bB0, bB1, bB2, bB3)
    B_LOAD(13, bB0, bB1, bB2, bB3)  K_MFMA(12, bA0, bA1, bA2, bA3)
    B_LOAD(14, bA0, bA1, bA2, bA3)  K_MFMA(13, bB0, bB1, bB2, bB3)
    B_LOAD(15, bB0, bB1, bB2, bB3)  K_MFMA(14, bA0, bA1, bA2, bA3)
    K_MFMA(15, bB0, bB1, bB2, bB3)
  }
#undef K_MFMA
#undef B_LOAD
#undef G_LOAD
#undef G_WRITE

  // ---- epilogue: scores -> m,Z,p -> PV partial (identical to R10) ----
  float a2r[4], wfr[4];
#pragma unroll
  for (int cf = 0; cf < 4; ++cf) {
    int col = wave * 64 + cf * 16 + l15;
    a2r[cf] = att2g[batch * NA + col];
    wfr[cf] = wfull[col];
  }
  float px[4][4];
#pragma unroll
  for (int rt = 0; rt < 4; ++rt)
#pragma unroll
    for (int r = 0; r < 4; ++r) px[rt][r] = 0.f;
#pragma unroll
  for (int cf = 0; cf < 4; ++cf) {
#pragma unroll
    for (int rt = 0; rt < 4; ++rt)
#pragma unroll
      for (int r = 0; r < 4; ++r) {
        float v = acc[rt][cf][r] + a2r[cf];
        px[rt][r] += fmaxf(v, 0.f) * wfr[cf];
      }
  }
#pragma unroll
  for (int rt = 0; rt < 4; ++rt)
#pragma unroll
    for (int r = 0; r < 4; ++r) {
      float p_ = px[rt][r];
      p_ += __shfl_xor(p_, 1);
      p_ += __shfl_xor(p_, 2);
      p_ += __shfl_xor(p_, 4);
      p_ += __shfl_xor(p_, 8);
      px[rt][r] = p_;
    }
  float* red = (float*)(smem + 65536);        // 512 f
  float* pl = (float*)(smem + 65536 + 2048);  // 64 f
  if (l15 == 0) {
#pragma unroll
    for (int rt = 0; rt < 4; ++rt)
#pragma unroll
      for (int r = 0; r < 4; ++r)
        red[wave * 64 + rt * 16 + lq * 4 + r] = px[rt][r];
  }
  __syncthreads();
  float sc = 0.f;
#pragma unroll
  for (int w8 = 0; w8 < 8; ++w8) sc += red[w8 * 64 + lane];
  if (t < 64) attg[blk * 64 + t] = sc;
  float m = sc;
#pragma unroll
  for (int off = 1; off < 64; off <<= 1) m = fmaxf(m, __shfl_xor(m, off));
  float p = expf(sc - m);
  float Z = p;
#pragma unroll
  for (int off = 1; off < 64; off <<= 1) Z += __shfl_xor(Z, off);
  if (t < 64) pl[t] = p;
  __syncthreads();

  {
    int half = t >> 8;
    int e = (t & 255) * 2;
    float o0 = 0.f, o1 = 0.f;
#pragma unroll
    for (int i = 0; i < 32; ++i) {
      int row = half * 32 + i;
      float pw = pl[row];
      int byt = (row * 1024 + e * 2) ^ ((row & 7) << 4);
      unsigned u = *reinterpret_cast<const unsigned*>(smem + byt);
      o0 += pw * __uint_as_float(u << 16);
      o1 += pw * __uint_as_float(u & 0xffff0000u);
    }
    __syncthreads();
    float2* xch = (float2*)red;
    if (half) xch[t - 256] = make_float2(o0, o1);
    __syncthreads();
    if (!half) {
      float2 hv = xch[t];
      *reinterpret_cast<float2*>(ogp + (long)blk * 512 + e) =
          make_float2(o0 + hv.x, o1 + hv.y);
    }
    if (t == 0) {
      mzg[blk * 2] = m;
      mzg[blk * 2 + 1] = Z;
    }
  }
}

// ---------------------------------------------------------------------------
// Kernel 3: merge 16 per-block (m,Z,o) partials per batch; emit weighted+alpha.
__global__ void k_final(const float* __restrict__ attg,
                        const float* __restrict__ ogp,
                        const float* __restrict__ mzg,
                        float* __restrict__ weighted,
                        float* __restrict__ alpha) {
  int b = blockIdx.x;   // 0..127
  int t = threadIdx.x;  // 512
  float mv[16], zv[16];
  float m = -__builtin_huge_valf();
#pragma unroll
  for (int i = 0; i < 16; ++i) {
    mv[i] = mzg[(b * 16 + i) * 2];
    zv[i] = mzg[(b * 16 + i) * 2 + 1];
    m = fmaxf(m, mv[i]);
  }
  float Z = 0.f;
#pragma unroll
  for (int i = 0; i < 16; ++i) {
    float s = expf(mv[i] - m);
    mv[i] = s;
    Z += s * zv[i];
  }
  float inv = 1.f / Z;
  float o = 0.f;
#pragma unroll
  for (int i = 0; i < 16; ++i) o += mv[i] * ogp[((long)b * 16 + i) * 512 + t];
  weighted[b * NE + t] = o * inv;
  alpha[b * NL + t] = expf(attg[b * NL + t] - m) * inv;
  alpha[b * NL + 512 + t] = expf(attg[b * NL + 512 + t] - m) * inv;
}

// ---------------------------------------------------------------------------
extern "C" void kernel_launch(void* const* d_in, const int* in_sizes, int n_in,
                              void* d_out, int out_size, void* d_ws, size_t ws_size,
                              hipStream_t stream) {
  const float* enc    = (const float*)d_in[0];  // [B,L,E]
  const float* dec    = (const float*)d_in[1];  // [B,D]
  const float* W_enc  = (const float*)d_in[2];  // [E,A]
  const float* b_enc  = (const float*)d_in[3];  // [A]
  const float* W_dec  = (const float*)d_in[4];  // [D,A]
  const float* b_dec  = (const float*)d_in[5];  // [A]
  const float* W_full = (const float*)d_in[6];  // [A]
  // d_in[7] = b_full: cancels in softmax, unused.

  float* out = (float*)d_out;
  float* weighted = out;                 // [B,E]
  float* alpha = out + NB * NE;          // [B,L]

  char* ws = (char*)d_ws;
  float* att2          = (float*)ws;                           // 256 KB
  unsigned short* Bpk  = (unsigned short*)(ws + (256 << 10));  // 512 KB
  float* attg          = (float*)(ws + (768 << 10));           // 512 KB
  float* ogp           = (float*)(ws + (1280 << 10));          // 4 MB
  float* mzg           = (float*)(ws + (5376 << 10));          // 16 KB

  hipLaunchKernelGGL(k_prep, dim3(192), dim3(512), 0, stream,
                     W_enc, Bpk, dec, W_dec, b_enc, b_dec, att2);
  hipLaunchKernelGGL(k_main, dim3(2048), dim3(512), 67840, stream,
                     enc, Bpk, att2, W_full, attg, ogp, mzg);
  hipLaunchKernelGGL(k_final, dim3(NB), dim3(512), 0, stream,
                     attg, ogp, mzg, weighted, alpha);
}